// Round 1
// baseline (594.326 us; speedup 1.0000x reference)
//
#include <hip/hip_runtime.h>
#include <hip/hip_bf16.h>
#include <cstdint>
#include <cstddef>

// Problem constants
#define T_DIM   2048
#define HID     4096
#define HQ      32
#define HKV     8
#define D_HEAD  128
#define QKV_N   6144   // 4096 Q + 1024 K + 1024 V
#define KOFF    4096
#define VOFF    5120

typedef __attribute__((ext_vector_type(8))) short short8;   // 8 bf16 (4 VGPRs)
typedef __attribute__((ext_vector_type(4))) float floatx4;  // MFMA C/D frag

__device__ __forceinline__ ushort f2bf(float f) {
    union { float f; uint u; } v; v.f = f;
    uint r = v.u + 0x7fffu + ((v.u >> 16) & 1u);  // RNE
    return (ushort)(r >> 16);
}
__device__ __forceinline__ float bf2f(ushort h) {
    union { uint u; float f; } v; v.u = ((uint)h) << 16; return v.f;
}
// 8 bf16 from 8B-aligned LDS
__device__ __forceinline__ short8 ld8(const ushort* p) {
    uint2 a = *(const uint2*)p, b = *(const uint2*)(p + 4);
    union { uint u[4]; short8 s; } x;
    x.u[0] = a.x; x.u[1] = a.y; x.u[2] = b.x; x.u[3] = b.y;
    return x.s;
}
// async global->LDS, 16B per lane. LDS dest must be wave-uniform base + lane*16.
__device__ __forceinline__ void gld_lds16(const ushort* g, ushort* l) {
    __builtin_amdgcn_global_load_lds(
        (__attribute__((address_space(1))) void*)(g),
        (__attribute__((address_space(3))) void*)(l), 16, 0, 0);
}

// ---------------- elementwise cast fp32 -> bf16 ----------------
__global__ void cast_f32_bf16(const float* __restrict__ in, ushort* __restrict__ out, int n) {
    int i = (blockIdx.x * blockDim.x + threadIdx.x) * 4;
    if (i < n) {
        float4 v = *(const float4*)(in + i);
        ushort4 o;
        o.x = f2bf(v.x); o.y = f2bf(v.y); o.z = f2bf(v.z); o.w = f2bf(v.w);
        *(ushort4*)(out + i) = o;
    }
}

// ---------------- transpose + cast: W[K][N] fp32 -> Wt[N][K] bf16 ----------------
__global__ __launch_bounds__(256) void transpose_cast(const float* __restrict__ W,
                                                      ushort* __restrict__ Wt, int K, int N) {
    __shared__ ushort tile[64][66];
    int n0 = blockIdx.x * 64, k0 = blockIdx.y * 64;
    int tx = threadIdx.x & 15, ty = threadIdx.x >> 4;  // 16 x 16
#pragma unroll
    for (int i = 0; i < 4; i++) {
        int r = ty + i * 16;  // k-row
        float4 v = *(const float4*)&W[(size_t)(k0 + r) * N + n0 + tx * 4];
        tile[tx * 4 + 0][r] = f2bf(v.x);
        tile[tx * 4 + 1][r] = f2bf(v.y);
        tile[tx * 4 + 2][r] = f2bf(v.z);
        tile[tx * 4 + 3][r] = f2bf(v.w);
    }
    __syncthreads();
#pragma unroll
    for (int i = 0; i < 4; i++) {
        int nr = ty + i * 16;  // n-row of output
        ushort4 o = *(const ushort4*)&tile[nr][tx * 4];
        *(ushort4*)&Wt[(size_t)(n0 + nr) * K + k0 + tx * 4] = o;
    }
}

// ---------------- transpose V slice of qkv -> VtG[kvh][d][t] (t contiguous) ----------------
__global__ void transpose_v(const ushort* __restrict__ qkv, ushort* __restrict__ VtG) {
    __shared__ ushort tile[32][33];
    int t0 = blockIdx.x * 32, d0 = blockIdx.y * 32, kvh = blockIdx.z;
    int tx = threadIdx.x & 31, ty = threadIdx.x >> 5;  // 32 x 8
#pragma unroll
    for (int i = 0; i < 4; i++) {
        int t = t0 + ty + i * 8;
        tile[ty + i * 8][tx] = qkv[(size_t)t * QKV_N + VOFF + kvh * D_HEAD + d0 + tx];
    }
    __syncthreads();
#pragma unroll
    for (int i = 0; i < 4; i++) {
        int d = d0 + ty + i * 8;
        VtG[((size_t)kvh * D_HEAD + d) * T_DIM + t0 + tx] = tile[tx][ty + i * 8];
    }
}

// ---------------- bf16 MFMA GEMM v2: C[M][N] = A[M][K] * Bt[N][K]^T ----------------
// 256x256 tile, 8 waves (2M x 4N, each wave owns 128x64), 16x16x32 MFMA.
// LDS = ring of 4 K32-subtile buffers per matrix (4 x 256x32 bf16 x 2 = 128 KiB).
// DEEP PIPELINE with COUNTED vmcnt: staging for K-step s+3 is issued during
// step s (A-half in phase A, B-half in phase B), so each load has ~5 phases of
// MFMA before its use; the per-step wait is s_waitcnt vmcnt(8) (8 outstanding
// = the {A,B} subtiles of steps s+2, s+3), never a full drain until the tail.
// Ring-slot safety: step s reads slot s&3; staging of s+3 writes slot (s-1)&3,
// whose readers finished before the end-of-step-(s-1) barrier.
// LDS swizzle (T2): 16B chunk c of row r stored at pos c ^ ((r>>1)&3), applied
// by pre-swizzling the GLOBAL source address (global_load_lds dest is linear);
// frag reads apply the same XOR -> <=2-way bank conflicts (free).
// Each phase: {ds_read frags | issue 2 gld_lds | bar | setprio(1) 16 MFMA} .
template <typename OutT>
__global__ __launch_bounds__(512, 2) void gemm_bt2(const ushort* __restrict__ A,
                                                   const ushort* __restrict__ Bt,
                                                   OutT* __restrict__ C,
                                                   int K, int lda, int ldb, int ldc) {
    __shared__ ushort As[4][256 * 32];   // 64 KiB
    __shared__ ushort Bs[4][256 * 32];   // 64 KiB
    int tid = threadIdx.x;
    int wid = tid >> 6, lane = tid & 63, quad = lane >> 4, l15 = lane & 15;
    int wr = wid >> 2, wc = wid & 3;     // 2M x 4N wave grid
    int m0 = blockIdx.x * 256, n0 = blockIdx.y * 256;

    floatx4 acc[8][4];
    floatx4 z = {0.f, 0.f, 0.f, 0.f};
#pragma unroll
    for (int i = 0; i < 8; i++)
#pragma unroll
        for (int j = 0; j < 4; j++) acc[i][j] = z;

    int NK = K >> 5;  // number of K32 steps (K=4096 -> 128)

    // staging source pointers: lane -> (row, chunk) with pre-swizzled chunk.
    // issue covers 128 rows x 4 chunks (8 KB); two issues per 256-row subtile.
    int r_st = tid >> 2;
    int c_st = (tid & 3) ^ ((tid >> 3) & 3);  // src chunk = pos ^ ((row>>1)&3)
    const ushort* gA0 = A  + (size_t)(m0 + r_st)       * lda + c_st * 8;
    const ushort* gA1 = A  + (size_t)(m0 + 128 + r_st) * lda + c_st * 8;
    const ushort* gB0 = Bt + (size_t)(n0 + r_st)       * ldb + c_st * 8;
    const ushort* gB1 = Bt + (size_t)(n0 + 128 + r_st) * ldb + c_st * 8;

    // prologue: stage steps 0,1,2 (12 issues), wait until step 0 landed (8 left)
    for (int s = 0; s < 3; ++s) {
        gld_lds16(gA0 + s * 32, &As[s][tid * 8]);
        gld_lds16(gA1 + s * 32, &As[s][4096 + tid * 8]);
        gld_lds16(gB0 + s * 32, &Bs[s][tid * 8]);
        gld_lds16(gB1 + s * 32, &Bs[s][4096 + tid * 8]);
    }
    asm volatile("s_waitcnt vmcnt(8)" ::: "memory");
    __builtin_amdgcn_s_barrier();

    short8 af[4];
    short8 bf[4];
    for (int s = 0; s < NK; ++s) {
        const ushort* sA = &As[s & 3][0];
        const ushort* sB = &Bs[s & 3][0];

        // ---- phase A: all B frags + A frags of m-half 0 ----
#pragma unroll
        for (int n = 0; n < 4; ++n) {
            int row = wc * 64 + n * 16 + l15;
            bf[n] = *(const short8*)&sB[row * 32 + ((quad ^ ((row >> 1) & 3)) * 8)];
        }
#pragma unroll
        for (int mi = 0; mi < 4; ++mi) {
            int row = wr * 128 + mi * 16 + l15;
            af[mi] = *(const short8*)&sA[row * 32 + ((quad ^ ((row >> 1) & 3)) * 8)];
        }
        if (s + 3 < NK) {  // stage A(s+3) into slot (s-1)&3 (freed at last barrier)
            gld_lds16(gA0 + (s + 3) * 32, &As[(s + 3) & 3][tid * 8]);
            gld_lds16(gA1 + (s + 3) * 32, &As[(s + 3) & 3][4096 + tid * 8]);
        }
        __builtin_amdgcn_sched_barrier(0);
        __builtin_amdgcn_s_barrier();
        __builtin_amdgcn_s_setprio(1);
#pragma unroll
        for (int n = 0; n < 4; ++n)
#pragma unroll
            for (int mi = 0; mi < 4; ++mi)
                acc[mi][n] = __builtin_amdgcn_mfma_f32_16x16x32_bf16(af[mi], bf[n], acc[mi][n], 0, 0, 0);
        __builtin_amdgcn_s_setprio(0);
        __builtin_amdgcn_sched_barrier(0);
        __builtin_amdgcn_s_barrier();

        // ---- phase B: A frags of m-half 1 (B frags reused) ----
#pragma unroll
        for (int mi = 0; mi < 4; ++mi) {
            int row = wr * 128 + 64 + mi * 16 + l15;
            af[mi] = *(const short8*)&sA[row * 32 + ((quad ^ ((row >> 1) & 3)) * 8)];
        }
        if (s + 3 < NK) {  // stage B(s+3)
            gld_lds16(gB0 + (s + 3) * 32, &Bs[(s + 3) & 3][tid * 8]);
            gld_lds16(gB1 + (s + 3) * 32, &Bs[(s + 3) & 3][4096 + tid * 8]);
        }
        __builtin_amdgcn_sched_barrier(0);
        __builtin_amdgcn_s_barrier();
        __builtin_amdgcn_s_setprio(1);
#pragma unroll
        for (int n = 0; n < 4; ++n)
#pragma unroll
            for (int mi = 0; mi < 4; ++mi)
                acc[4 + mi][n] = __builtin_amdgcn_mfma_f32_16x16x32_bf16(af[mi], bf[n], acc[4 + mi][n], 0, 0, 0);
        __builtin_amdgcn_s_setprio(0);
        // counted wait: ensure step s+1 landed; keep {A,B}(s+2),(s+3) in flight
        if (s < NK - 3)       asm volatile("s_waitcnt vmcnt(8)" ::: "memory");
        else if (s == NK - 3) asm volatile("s_waitcnt vmcnt(4)" ::: "memory");
        else if (s == NK - 2) asm volatile("s_waitcnt vmcnt(0)" ::: "memory");
        __builtin_amdgcn_sched_barrier(0);
        __builtin_amdgcn_s_barrier();
    }

    // epilogue: C row = (lane>>4)*4 + reg, col = lane&15 within each 16x16 tile
#pragma unroll
    for (int i = 0; i < 8; ++i) {
        int row0 = m0 + wr * 128 + i * 16 + quad * 4;
#pragma unroll
        for (int j = 0; j < 4; ++j) {
            int col = n0 + wc * 64 + j * 16 + l15;
#pragma unroll
            for (int r = 0; r < 4; ++r) {
                float v = acc[i][j][r];
                if constexpr (sizeof(OutT) == 2)
                    C[(size_t)(row0 + r) * ldc + col] = (OutT)f2bf(v);
                else
                    C[(size_t)(row0 + r) * ldc + col] = v;
            }
        }
    }
}

// ---------------- RoPE in-place on Q and K slices of qkv ----------------
__global__ void rope_kernel(ushort* __restrict__ qkv, const float* __restrict__ cosb,
                            const float* __restrict__ sinb) {
    int t = blockIdx.x;
    ushort* row = qkv + (size_t)t * QKV_N;
    const float* cr = cosb + (size_t)t * D_HEAD;
    const float* sr = sinb + (size_t)t * D_HEAD;
    for (int c = threadIdx.x; c < 2560; c += 256) {
        int slice = c >> 6, d = c & 63;
        int col = slice * 128 + d;
        float x0 = bf2f(row[col]), x1 = bf2f(row[col + 64]);
        float cs = cr[d], sn = sr[d];
        row[col] = f2bf(x0 * cs - x1 * sn);
        row[col + 64] = f2bf(x1 * cs + x0 * sn);
    }
}

// ---------------- flash-style causal GQA attention ----------------
#define PS_STRIDE 68

__global__ __launch_bounds__(256, 2) void attn_kernel(const ushort* __restrict__ qkv,
                                                      const ushort* __restrict__ VtG,
                                                      ushort* __restrict__ attn) {
    __shared__ ushort Ks[64 * 128];         // 16384 B, swizzled
    __shared__ ushort Vt[128 * 64];         // 16384 B, swizzled
    __shared__ ushort Ps[128 * PS_STRIDE];  // 17408 B  (total 50176 B -> 3 blocks/CU)

    int qt = (gridDim.x - 1) - blockIdx.x;  // heavy tiles dispatch first
    int h = blockIdx.y;
    int q0 = qt * 128;
    int kbmax = 2 * qt + 1;
    int tid = threadIdx.x, w = tid >> 6, lane = tid & 63, quad = lane >> 4, l15 = lane & 15;
    int kvh = h >> 2;                       // GQA group of 4

    const ushort* kbase = qkv + (size_t)KOFF + (size_t)kvh * D_HEAD;
    const ushort* vbase = VtG + (size_t)kvh * D_HEAD * T_DIM;

    const ushort* ksrc[4];
    const ushort* vsrc[4];
#pragma unroll
    for (int i = 0; i < 4; i++) {
        int cid = i * 256 + tid;
        int kr = cid >> 4, kp = cid & 15, kc = kp ^ (kr & 15);
        ksrc[i] = kbase + (size_t)kr * QKV_N + kc * 8;
        int vr = cid >> 3, vp = cid & 7, vc = vp ^ (vr & 7);
        vsrc[i] = vbase + (size_t)vr * T_DIM + vc * 8;
    }

    // prologue: issue K(0) loads (latency covered by the Q-frag loads below)
#pragma unroll
    for (int i = 0; i < 4; i++) {
        gld_lds16(ksrc[i], &Ks[(i * 256 + tid) * 8]);
        ksrc[i] += (size_t)64 * QKV_N;
    }

    // Q A-frags for both strips, direct from global (one-time scattered read)
    short8 qf[2][4];
#pragma unroll
    for (int s = 0; s < 2; s++) {
        const ushort* qrow = qkv + (size_t)(q0 + s * 64 + w * 16 + l15) * QKV_N + h * D_HEAD + quad * 8;
#pragma unroll
        for (int ks = 0; ks < 4; ks++)
            qf[s][ks] = *(const short8*)(qrow + ks * 32);
    }

    floatx4 o[2][8];
    floatx4 z = {0.f, 0.f, 0.f, 0.f};
#pragma unroll
    for (int s = 0; s < 2; s++)
#pragma unroll
        for (int j = 0; j < 8; j++) o[s][j] = z;
    float lsum[2][4] = {{0.f, 0.f, 0.f, 0.f}, {0.f, 0.f, 0.f, 0.f}};

    const float scale_l2e = 0.08838834764831845f * 1.4426950408889634f;  // D^-0.5 * log2(e)
    const float BOUND = 24.0f;

    __syncthreads();  // drain K(0)

    for (int kb = 0; kb <= kbmax; kb++) {
        bool act0 = (kb <= 2 * qt);  // strip0 fully masked on the final iteration

        // issue V(kb) loads (drained at mid-barrier; covered by QK compute)
#pragma unroll
        for (int i = 0; i < 4; i++) {
            gld_lds16(vsrc[i], &Vt[(i * 256 + tid) * 8]);
            vsrc[i] += 64;
        }

        // S = Q K^T for both strips; swizzled K frag reads shared across strips
        floatx4 sc[2][4];
#pragma unroll
        for (int s = 0; s < 2; s++)
#pragma unroll
            for (int jt = 0; jt < 4; jt++) sc[s][jt] = z;
#pragma unroll
        for (int ks = 0; ks < 4; ks++) {
#pragma unroll
            for (int jt = 0; jt < 4; jt++) {
                short8 kf = ld8(&Ks[(jt * 16 + l15) * 128 + (((ks * 4 + quad) ^ l15) * 8)]);
                if (act0)
                    sc[0][jt] = __builtin_amdgcn_mfma_f32_16x16x32_bf16(qf[0][ks], kf, sc[0][jt], 0, 0, 0);
                sc[1][jt] = __builtin_amdgcn_mfma_f32_16x16x32_bf16(qf[1][ks], kf, sc[1][jt], 0, 0, 0);
            }
        }

        // fixed-bound softmax; Ps rows are wave-private (lgkmcnt handles RAW)
#pragma unroll
        for (int s = 0; s < 2; s++) {
            if (s == 0 && !act0) continue;
            bool diag = (kb == 2 * qt + s);
#pragma unroll
            for (int r = 0; r < 4; r++) {
                int rloc = w * 16 + quad * 4 + r;  // row within strip
#pragma unroll
                for (int jt = 0; jt < 4; jt++) {
                    float v = fmaf(sc[s][jt][r], scale_l2e, -BOUND);
                    if (diag && (jt * 16 + l15 > rloc)) v = -1e30f;
                    float p = exp2f(v);
                    lsum[s][r] += p;
                    Ps[(s * 64 + rloc) * PS_STRIDE + jt * 16 + l15] = f2bf(p);
                }
            }
        }

        __syncthreads();  // drain V(kb); all waves' Ks reads complete

        // issue K(kb+1) loads (drained at end-barrier; covered by PV compute)
        if (kb < kbmax) {
#pragma unroll
            for (int i = 0; i < 4; i++) {
                gld_lds16(ksrc[i], &Ks[(i * 256 + tid) * 8]);
                ksrc[i] += (size_t)64 * QKV_N;
            }
        }

        // O += P V ; swizzled V frag reads shared across strips
#pragma unroll
        for (int ks2 = 0; ks2 < 2; ks2++) {
            short8 pf0 = ld8(&Ps[(w * 16 + l15) * PS_STRIDE + ks2 * 32 + quad * 8]);
            short8 pf1 = ld8(&Ps[(64 + w * 16 + l15) * PS_STRIDE + ks2 * 32 + quad * 8]);
#pragma unroll
            for (int jt = 0; jt < 8; jt++) {
                short8 vf = ld8(&Vt[(jt * 16 + l15) * 64 + (((ks2 * 4 + quad) ^ (l15 & 7)) * 8)]);
                if (act0)
                    o[0][jt] = __builtin_amdgcn_mfma_f32_16x16x32_bf16(pf0, vf, o[0][jt], 0, 0, 0);
                o[1][jt] = __builtin_amdgcn_mfma_f32_16x16x32_bf16(pf1, vf, o[1][jt], 0, 0, 0);
            }
        }

        __syncthreads();  // drain K(kb+1); all waves' Vt/Ps reads complete
    }

    // epilogue: one shuffle reduction per row, normalize, store bf16
#pragma unroll
    for (int s = 0; s < 2; s++) {
#pragma unroll
        for (int r = 0; r < 4; r++) {
            float l = lsum[s][r];
#pragma unroll
            for (int mk = 1; mk <= 8; mk <<= 1) l += __shfl_xor(l, mk);
            float inv = 1.f / l;
            int trow = q0 + s * 64 + w * 16 + quad * 4 + r;
            ushort* orow = attn + (size_t)trow * (HQ * D_HEAD) + h * D_HEAD;
#pragma unroll
            for (int jt = 0; jt < 8; jt++)
                orow[jt * 16 + l15] = f2bf(o[s][jt][r] * inv);
        }
    }
}

// ---------------- launch ----------------
extern "C" void kernel_launch(void* const* d_in, const int* in_sizes, int n_in,
                              void* d_out, int out_size, void* d_ws, size_t ws_size,
                              hipStream_t stream) {
    const float* hidden = (const float*)d_in[0];
    const float* cosb = (const float*)d_in[2];
    const float* sinb = (const float*)d_in[3];
    const float* Wq = (const float*)d_in[4];
    const float* Wk = (const float*)d_in[5];
    const float* Wv = (const float*)d_in[6];
    const float* Wo = (const float*)d_in[7];
    float* out = (float*)d_out;

    char* ws = (char*)d_ws;
    ushort* hiddenB = (ushort*)(ws);                          // 16 MB: T x HID bf16
    ushort* WqkvT   = (ushort*)(ws + (size_t)(16u << 20));    // 48 MB: [6144][4096] bf16
    ushort* WoT     = (ushort*)(ws + (size_t)(64u << 20));    // 32 MB: [4096][4096] bf16
    ushort* qkv     = (ushort*)(ws + (size_t)(96u << 20));    // 24 MB: T x 6144 bf16
    ushort* attnO   = (ushort*)(ws + (size_t)(120u << 20));   // 16 MB: T x 4096 bf16
    ushort* VtG     = (ushort*)(ws + (size_t)(136u << 20));   // 4 MB: [HKV][128][2048] bf16
    // total 140 MB

    cast_f32_bf16<<<8192, 256, 0, stream>>>(hidden, hiddenB, T_DIM * HID);
    transpose_cast<<<dim3(64, 64), 256, 0, stream>>>(Wq, WqkvT, HID, 4096);
    transpose_cast<<<dim3(16, 64), 256, 0, stream>>>(Wk, WqkvT + (size_t)4096 * HID, HID, 1024);
    transpose_cast<<<dim3(16, 64), 256, 0, stream>>>(Wv, WqkvT + (size_t)5120 * HID, HID, 1024);
    transpose_cast<<<dim3(64, 64), 256, 0, stream>>>(Wo, WoT, HID, 4096);

    // qkv = hidden @ [Wq|Wk|Wv]   (M=2048, N=6144, K=4096), bf16 out
    gemm_bt2<ushort><<<dim3(8, 24), 512, 0, stream>>>(hiddenB, WqkvT, qkv,
                                                      HID, HID, HID, QKV_N);
    rope_kernel<<<T_DIM, 256, 0, stream>>>(qkv, cosb, sinb);
    transpose_v<<<dim3(64, 4, 8), 256, 0, stream>>>(qkv, VtG);
    attn_kernel<<<dim3(T_DIM / 128, HQ), 256, 0, stream>>>(qkv, VtG, attnO);
    // out = attnO @ Wo  (M=2048, N=4096, K=4096), fp32 out
    gemm_bt2<float><<<dim3(8, 16), 512, 0, stream>>>(attnO, WoT, out,
                                                     HID, HID, HID, HID);
}

// Round 2
// 569.767 us; speedup vs baseline: 1.0431x; 1.0431x over previous
//
#include <hip/hip_runtime.h>
#include <hip/hip_bf16.h>
#include <cstdint>
#include <cstddef>

// Problem constants
#define T_DIM   2048
#define HID     4096
#define HQ      32
#define HKV     8
#define D_HEAD  128
#define QKV_N   6144   // 4096 Q + 1024 K + 1024 V
#define KOFF    4096
#define VOFF    5120

typedef __attribute__((ext_vector_type(8))) short short8;   // 8 bf16 (4 VGPRs)
typedef __attribute__((ext_vector_type(4))) float floatx4;  // MFMA C/D frag

__device__ __forceinline__ ushort f2bf(float f) {
    union { float f; uint u; } v; v.f = f;
    uint r = v.u + 0x7fffu + ((v.u >> 16) & 1u);  // RNE
    return (ushort)(r >> 16);
}
__device__ __forceinline__ float bf2f(ushort h) {
    union { uint u; float f; } v; v.u = ((uint)h) << 16; return v.f;
}
// 8 bf16 from 8B-aligned LDS
__device__ __forceinline__ short8 ld8(const ushort* p) {
    uint2 a = *(const uint2*)p, b = *(const uint2*)(p + 4);
    union { uint u[4]; short8 s; } x;
    x.u[0] = a.x; x.u[1] = a.y; x.u[2] = b.x; x.u[3] = b.y;
    return x.s;
}
// async global->LDS, 16B per lane. LDS dest must be wave-uniform base + lane*16.
__device__ __forceinline__ void gld_lds16(const ushort* g, ushort* l) {
    __builtin_amdgcn_global_load_lds(
        (__attribute__((address_space(1))) void*)(g),
        (__attribute__((address_space(3))) void*)(l), 16, 0, 0);
}

// ---------------- elementwise cast fp32 -> bf16 ----------------
__global__ void cast_f32_bf16(const float* __restrict__ in, ushort* __restrict__ out, int n) {
    int i = (blockIdx.x * blockDim.x + threadIdx.x) * 4;
    if (i < n) {
        float4 v = *(const float4*)(in + i);
        ushort4 o;
        o.x = f2bf(v.x); o.y = f2bf(v.y); o.z = f2bf(v.z); o.w = f2bf(v.w);
        *(ushort4*)(out + i) = o;
    }
}

// ---------------- transpose + cast: W[K][N] fp32 -> Wt[N][K] bf16 ----------------
__global__ __launch_bounds__(256) void transpose_cast(const float* __restrict__ W,
                                                      ushort* __restrict__ Wt, int K, int N) {
    __shared__ ushort tile[64][66];
    int n0 = blockIdx.x * 64, k0 = blockIdx.y * 64;
    int tx = threadIdx.x & 15, ty = threadIdx.x >> 4;  // 16 x 16
#pragma unroll
    for (int i = 0; i < 4; i++) {
        int r = ty + i * 16;  // k-row
        float4 v = *(const float4*)&W[(size_t)(k0 + r) * N + n0 + tx * 4];
        tile[tx * 4 + 0][r] = f2bf(v.x);
        tile[tx * 4 + 1][r] = f2bf(v.y);
        tile[tx * 4 + 2][r] = f2bf(v.z);
        tile[tx * 4 + 3][r] = f2bf(v.w);
    }
    __syncthreads();
#pragma unroll
    for (int i = 0; i < 4; i++) {
        int nr = ty + i * 16;  // n-row of output
        ushort4 o = *(const ushort4*)&tile[nr][tx * 4];
        *(ushort4*)&Wt[(size_t)(n0 + nr) * K + k0 + tx * 4] = o;
    }
}

// ---------------- transpose V slice of qkv -> VtG[kvh][d][t] (t contiguous) ----------------
__global__ void transpose_v(const ushort* __restrict__ qkv, ushort* __restrict__ VtG) {
    __shared__ ushort tile[32][33];
    int t0 = blockIdx.x * 32, d0 = blockIdx.y * 32, kvh = blockIdx.z;
    int tx = threadIdx.x & 31, ty = threadIdx.x >> 5;  // 32 x 8
#pragma unroll
    for (int i = 0; i < 4; i++) {
        int t = t0 + ty + i * 8;
        tile[ty + i * 8][tx] = qkv[(size_t)t * QKV_N + VOFF + kvh * D_HEAD + d0 + tx];
    }
    __syncthreads();
#pragma unroll
    for (int i = 0; i < 4; i++) {
        int d = d0 + ty + i * 8;
        VtG[((size_t)kvh * D_HEAD + d) * T_DIM + t0 + tx] = tile[tx][ty + i * 8];
    }
}

// ======== 256x256 8-phase GEMM (m201-template port): C = A * Bt^T ========
// BK=64, 2-slot dbuf LDS (128 KiB), 8 waves as 2M x 4N (wave tile 128x64).
// Per K-tile: 4 phases, each = { ds_read frags (12 in p0: all B cached to regs
// + A quarter; else 4), issue one half-tile stage (2 gld_lds), barrier,
// lgkmcnt(0), setprio(1), 16 MFMA (one 32-row quadrant x K=64), setprio(0),
// counted vmcnt on even phases, barrier }.
// Staging: tile t+1 staged during tile t's phases into the idle slot, order
// [A-lo(j0), B-lo(j0), B-hi(j1), A-hi(j1)]; A quarters are consumed in phase
// order so A-hi (phase 3 issue) is first needed at next tile's phase 2 and is
// drained by the vmcnt(4) at that tile's phase-1 end. vmcnt(2) at phase-3 end
// drains everything needed for the next tile's phase 0 (all >=1 phase old).
// LDS swizzle: 16B chunk c of row r stored at c ^ (r&7); applied by
// pre-swizzling the GLOBAL source chunk (gld_lds dest must stay linear);
// frag ds_reads use the same XOR -> even bank spread (conflict-free).
template <typename OutT>
__global__ __launch_bounds__(512, 2) void gemm256(const ushort* __restrict__ A,
                                                  const ushort* __restrict__ Bt,
                                                  OutT* __restrict__ C,
                                                  int K, int lda, int ldb, int ldc) {
    __shared__ ushort As[2][16384];   // [slot][half*8192 + row*64 + chunk*8]
    __shared__ ushort Bs[2][16384];
    int tid = threadIdx.x;
    int wid = tid >> 6, lane = tid & 63, quad = lane >> 4, l15 = lane & 15;
    int wr = wid >> 2, wc = wid & 3;           // 2M x 4N wave grid
    int bh = wc >> 1, br = (wc & 1) * 64;      // B half + row base for this wave
    int m0 = blockIdx.x * 256, n0 = blockIdx.y * 256;
    int sw = (l15 & 7);                        // frag-read chunk XOR

    floatx4 acc[8][4];
    floatx4 z = {0.f, 0.f, 0.f, 0.f};
#pragma unroll
    for (int i = 0; i < 8; i++)
#pragma unroll
        for (int j = 0; j < 4; j++) acc[i][j] = z;

    int NT = K >> 6;  // K-tiles of 64 (4096 -> 64)

    // staging source base: lane covers row r8 (of a 64-row quarter-issue),
    // pre-swizzled chunk csw; dest is linear tid*16B.
    int r8 = tid >> 3;
    int csw = (tid & 7) ^ (r8 & 7);
    const ushort* sA = A  + (size_t)(m0 + r8) * lda + csw * 8;
    const ushort* sB = Bt + (size_t)(n0 + r8) * ldb + csw * 8;

    // prologue: stage tile 0 into slot 0, order [A.j0s, B.j0s, B.j1s, A.j1s]
    gld_lds16(sA,                          &As[0][tid * 8]);
    gld_lds16(sA + (size_t)128 * lda,      &As[0][8192 + tid * 8]);
    gld_lds16(sB,                          &Bs[0][tid * 8]);
    gld_lds16(sB + (size_t)128 * ldb,      &Bs[0][8192 + tid * 8]);
    gld_lds16(sB + (size_t)64 * ldb,       &Bs[0][4096 + tid * 8]);
    gld_lds16(sB + (size_t)192 * ldb,      &Bs[0][12288 + tid * 8]);
    gld_lds16(sA + (size_t)64 * lda,       &As[0][4096 + tid * 8]);
    gld_lds16(sA + (size_t)192 * lda,      &As[0][12288 + tid * 8]);
    asm volatile("s_waitcnt vmcnt(2)" ::: "memory");
    __builtin_amdgcn_sched_barrier(0);
    __builtin_amdgcn_s_barrier();

    short8 bfr[4][2];   // B frags cached for the whole K-tile (32 VGPR)
    short8 af[2][2];

    for (int t = 0; t < NT; ++t) {
        int slot = t & 1, ns = slot ^ 1;
        const ushort* tA = &As[slot][wr * 8192];
        const ushort* tB = &Bs[slot][bh * 8192];
        size_t ko = (size_t)(t + 1) * 64;
        bool pf = (t + 1 < NT);

        // ================= phase 0 : quadrant 0 =================
#pragma unroll
        for (int nf = 0; nf < 4; ++nf)
#pragma unroll
            for (int kh = 0; kh < 2; ++kh)
                bfr[nf][kh] = *(const short8*)&tB[(br + nf * 16 + l15) * 64 +
                                                  (((quad + kh * 4) ^ sw) * 8)];
#pragma unroll
        for (int mi = 0; mi < 2; ++mi)
#pragma unroll
            for (int kh = 0; kh < 2; ++kh)
                af[mi][kh] = *(const short8*)&tA[(mi * 16 + l15) * 64 +
                                                 (((quad + kh * 4) ^ sw) * 8)];
        if (pf) {
            gld_lds16(sA + ko,                     &As[ns][tid * 8]);
            gld_lds16(sA + (size_t)128 * lda + ko, &As[ns][8192 + tid * 8]);
        }
        __builtin_amdgcn_sched_barrier(0);
        __builtin_amdgcn_s_barrier();
        asm volatile("s_waitcnt lgkmcnt(0)" ::: "memory");
        __builtin_amdgcn_sched_barrier(0);
        __builtin_amdgcn_s_setprio(1);
#pragma unroll
        for (int nf = 0; nf < 4; ++nf)
#pragma unroll
            for (int mi = 0; mi < 2; ++mi)
#pragma unroll
                for (int kh = 0; kh < 2; ++kh)
                    acc[mi][nf] = __builtin_amdgcn_mfma_f32_16x16x32_bf16(af[mi][kh], bfr[nf][kh], acc[mi][nf], 0, 0, 0);
        __builtin_amdgcn_s_setprio(0);
        __builtin_amdgcn_sched_barrier(0);
        __builtin_amdgcn_s_barrier();

        // ================= phase 1 : quadrant 1 =================
#pragma unroll
        for (int mi = 0; mi < 2; ++mi)
#pragma unroll
            for (int kh = 0; kh < 2; ++kh)
                af[mi][kh] = *(const short8*)&tA[(32 + mi * 16 + l15) * 64 +
                                                 (((quad + kh * 4) ^ sw) * 8)];
        if (pf) {
            gld_lds16(sB + ko,                     &Bs[ns][tid * 8]);
            gld_lds16(sB + (size_t)128 * ldb + ko, &Bs[ns][8192 + tid * 8]);
        }
        __builtin_amdgcn_sched_barrier(0);
        __builtin_amdgcn_s_barrier();
        asm volatile("s_waitcnt lgkmcnt(0)" ::: "memory");
        __builtin_amdgcn_sched_barrier(0);
        __builtin_amdgcn_s_setprio(1);
#pragma unroll
        for (int nf = 0; nf < 4; ++nf)
#pragma unroll
            for (int mi = 0; mi < 2; ++mi)
#pragma unroll
                for (int kh = 0; kh < 2; ++kh)
                    acc[2 + mi][nf] = __builtin_amdgcn_mfma_f32_16x16x32_bf16(af[mi][kh], bfr[nf][kh], acc[2 + mi][nf], 0, 0, 0);
        __builtin_amdgcn_s_setprio(0);
        __builtin_amdgcn_sched_barrier(0);
        if (pf) asm volatile("s_waitcnt vmcnt(4)" ::: "memory");
        else    asm volatile("s_waitcnt vmcnt(0)" ::: "memory");
        __builtin_amdgcn_sched_barrier(0);
        __builtin_amdgcn_s_barrier();

        // ================= phase 2 : quadrant 2 =================
#pragma unroll
        for (int mi = 0; mi < 2; ++mi)
#pragma unroll
            for (int kh = 0; kh < 2; ++kh)
                af[mi][kh] = *(const short8*)&tA[(64 + mi * 16 + l15) * 64 +
                                                 (((quad + kh * 4) ^ sw) * 8)];
        if (pf) {
            gld_lds16(sB + (size_t)64 * ldb + ko,  &Bs[ns][4096 + tid * 8]);
            gld_lds16(sB + (size_t)192 * ldb + ko, &Bs[ns][12288 + tid * 8]);
        }
        __builtin_amdgcn_sched_barrier(0);
        __builtin_amdgcn_s_barrier();
        asm volatile("s_waitcnt lgkmcnt(0)" ::: "memory");
        __builtin_amdgcn_sched_barrier(0);
        __builtin_amdgcn_s_setprio(1);
#pragma unroll
        for (int nf = 0; nf < 4; ++nf)
#pragma unroll
            for (int mi = 0; mi < 2; ++mi)
#pragma unroll
                for (int kh = 0; kh < 2; ++kh)
                    acc[4 + mi][nf] = __builtin_amdgcn_mfma_f32_16x16x32_bf16(af[mi][kh], bfr[nf][kh], acc[4 + mi][nf], 0, 0, 0);
        __builtin_amdgcn_s_setprio(0);
        __builtin_amdgcn_sched_barrier(0);
        __builtin_amdgcn_s_barrier();

        // ================= phase 3 : quadrant 3 =================
#pragma unroll
        for (int mi = 0; mi < 2; ++mi)
#pragma unroll
            for (int kh = 0; kh < 2; ++kh)
                af[mi][kh] = *(const short8*)&tA[(96 + mi * 16 + l15) * 64 +
                                                 (((quad + kh * 4) ^ sw) * 8)];
        if (pf) {
            gld_lds16(sA + (size_t)64 * lda + ko,  &As[ns][4096 + tid * 8]);
            gld_lds16(sA + (size_t)192 * lda + ko, &As[ns][12288 + tid * 8]);
        }
        __builtin_amdgcn_sched_barrier(0);
        __builtin_amdgcn_s_barrier();
        asm volatile("s_waitcnt lgkmcnt(0)" ::: "memory");
        __builtin_amdgcn_sched_barrier(0);
        __builtin_amdgcn_s_setprio(1);
#pragma unroll
        for (int nf = 0; nf < 4; ++nf)
#pragma unroll
            for (int mi = 0; mi < 2; ++mi)
#pragma unroll
                for (int kh = 0; kh < 2; ++kh)
                    acc[6 + mi][nf] = __builtin_amdgcn_mfma_f32_16x16x32_bf16(af[mi][kh], bfr[nf][kh], acc[6 + mi][nf], 0, 0, 0);
        __builtin_amdgcn_s_setprio(0);
        __builtin_amdgcn_sched_barrier(0);
        if (pf) asm volatile("s_waitcnt vmcnt(2)" ::: "memory");
        __builtin_amdgcn_sched_barrier(0);
        __builtin_amdgcn_s_barrier();
    }

    // epilogue: C row = (lane>>4)*4 + reg, col = lane&15 within each 16x16 tile
#pragma unroll
    for (int i = 0; i < 8; ++i) {
        int row0 = m0 + wr * 128 + i * 16 + quad * 4;
#pragma unroll
        for (int j = 0; j < 4; ++j) {
            int col = n0 + wc * 64 + j * 16 + l15;
#pragma unroll
            for (int r = 0; r < 4; ++r) {
                float v = acc[i][j][r];
                if constexpr (sizeof(OutT) == 2)
                    C[(size_t)(row0 + r) * ldc + col] = (OutT)f2bf(v);
                else
                    C[(size_t)(row0 + r) * ldc + col] = v;
            }
        }
    }
}

// ---------------- 128x128 GEMM (round-0, known-good): used for O-proj ----------------
template <typename OutT>
__global__ __launch_bounds__(256) void gemm_bt(const ushort* __restrict__ A,
                                               const ushort* __restrict__ Bt,
                                               OutT* __restrict__ C,
                                               int K, int lda, int ldb, int ldc) {
    __shared__ ushort As[2][128 * 32];
    __shared__ ushort Bs[2][128 * 32];
    int tid = threadIdx.x;
    int w = tid >> 6, lane = tid & 63, quad = lane >> 4, l15 = lane & 15;
    int wr = (w >> 1) * 64, wc = (w & 1) * 64;
    int m0 = blockIdx.x * 128, n0 = blockIdx.y * 128;

    floatx4 acc[4][4];
    floatx4 z = {0.f, 0.f, 0.f, 0.f};
#pragma unroll
    for (int i = 0; i < 4; i++)
#pragma unroll
        for (int j = 0; j < 4; j++) acc[i][j] = z;

    int arow = tid >> 2, ac = (tid & 3) * 8;
    const ushort* gA0 = A + (size_t)(m0 + arow) * lda + ac;
    const ushort* gA1 = A + (size_t)(m0 + arow + 64) * lda + ac;
    const ushort* gB0 = Bt + (size_t)(n0 + arow) * ldb + ac;
    const ushort* gB1 = Bt + (size_t)(n0 + arow + 64) * ldb + ac;

    gld_lds16(gA0, &As[0][tid * 8]);
    gld_lds16(gA1, &As[0][64 * 32 + tid * 8]);
    gld_lds16(gB0, &Bs[0][tid * 8]);
    gld_lds16(gB1, &Bs[0][64 * 32 + tid * 8]);
    gA0 += 32; gA1 += 32; gB0 += 32; gB1 += 32;

    int cur = 0;
    for (int k0 = 0; k0 < K; k0 += 32, cur ^= 1) {
        __syncthreads();
        if (k0 + 32 < K) {
            gld_lds16(gA0, &As[cur ^ 1][tid * 8]);
            gld_lds16(gA1, &As[cur ^ 1][64 * 32 + tid * 8]);
            gld_lds16(gB0, &Bs[cur ^ 1][tid * 8]);
            gld_lds16(gB1, &Bs[cur ^ 1][64 * 32 + tid * 8]);
            gA0 += 32; gA1 += 32; gB0 += 32; gB1 += 32;
        }

        short8 af[4];
#pragma unroll
        for (int i = 0; i < 4; i++)
            af[i] = *(const short8*)&As[cur][(wr + i * 16 + l15) * 32 + quad * 8];
#pragma unroll
        for (int j = 0; j < 4; j++) {
            short8 bf = *(const short8*)&Bs[cur][(wc + j * 16 + l15) * 32 + quad * 8];
#pragma unroll
            for (int i = 0; i < 4; i++)
                acc[i][j] = __builtin_amdgcn_mfma_f32_16x16x32_bf16(af[i], bf, acc[i][j], 0, 0, 0);
        }
    }

#pragma unroll
    for (int i = 0; i < 4; i++) {
        int row0 = m0 + wr + i * 16 + quad * 4;
#pragma unroll
        for (int j = 0; j < 4; j++) {
            int col = n0 + wc + j * 16 + l15;
#pragma unroll
            for (int r = 0; r < 4; r++) {
                float v = acc[i][j][r];
                if constexpr (sizeof(OutT) == 2)
                    C[(size_t)(row0 + r) * ldc + col] = (OutT)f2bf(v);
                else
                    C[(size_t)(row0 + r) * ldc + col] = v;
            }
        }
    }
}

// ---------------- RoPE in-place on Q and K slices of qkv ----------------
__global__ void rope_kernel(ushort* __restrict__ qkv, const float* __restrict__ cosb,
                            const float* __restrict__ sinb) {
    int t = blockIdx.x;
    ushort* row = qkv + (size_t)t * QKV_N;
    const float* cr = cosb + (size_t)t * D_HEAD;
    const float* sr = sinb + (size_t)t * D_HEAD;
    for (int c = threadIdx.x; c < 2560; c += 256) {
        int slice = c >> 6, d = c & 63;
        int col = slice * 128 + d;
        float x0 = bf2f(row[col]), x1 = bf2f(row[col + 64]);
        float cs = cr[d], sn = sr[d];
        row[col] = f2bf(x0 * cs - x1 * sn);
        row[col + 64] = f2bf(x1 * cs + x0 * sn);
    }
}

// ---------------- flash-style causal GQA attention ----------------
#define PS_STRIDE 68

__global__ __launch_bounds__(256, 2) void attn_kernel(const ushort* __restrict__ qkv,
                                                      const ushort* __restrict__ VtG,
                                                      ushort* __restrict__ attn) {
    __shared__ ushort Ks[64 * 128];         // 16384 B, swizzled
    __shared__ ushort Vt[128 * 64];         // 16384 B, swizzled
    __shared__ ushort Ps[128 * PS_STRIDE];  // 17408 B  (total 50176 B -> 3 blocks/CU)

    int qt = (gridDim.x - 1) - blockIdx.x;  // heavy tiles dispatch first
    int h = blockIdx.y;
    int q0 = qt * 128;
    int kbmax = 2 * qt + 1;
    int tid = threadIdx.x, w = tid >> 6, lane = tid & 63, quad = lane >> 4, l15 = lane & 15;
    int kvh = h >> 2;                       // GQA group of 4

    const ushort* kbase = qkv + (size_t)KOFF + (size_t)kvh * D_HEAD;
    const ushort* vbase = VtG + (size_t)kvh * D_HEAD * T_DIM;

    const ushort* ksrc[4];
    const ushort* vsrc[4];
#pragma unroll
    for (int i = 0; i < 4; i++) {
        int cid = i * 256 + tid;
        int kr = cid >> 4, kp = cid & 15, kc = kp ^ (kr & 15);
        ksrc[i] = kbase + (size_t)kr * QKV_N + kc * 8;
        int vr = cid >> 3, vp = cid & 7, vc = vp ^ (vr & 7);
        vsrc[i] = vbase + (size_t)vr * T_DIM + vc * 8;
    }

    // prologue: issue K(0) loads (latency covered by the Q-frag loads below)
#pragma unroll
    for (int i = 0; i < 4; i++) {
        gld_lds16(ksrc[i], &Ks[(i * 256 + tid) * 8]);
        ksrc[i] += (size_t)64 * QKV_N;
    }

    // Q A-frags for both strips, direct from global (one-time scattered read)
    short8 qf[2][4];
#pragma unroll
    for (int s = 0; s < 2; s++) {
        const ushort* qrow = qkv + (size_t)(q0 + s * 64 + w * 16 + l15) * QKV_N + h * D_HEAD + quad * 8;
#pragma unroll
        for (int ks = 0; ks < 4; ks++)
            qf[s][ks] = *(const short8*)(qrow + ks * 32);
    }

    floatx4 o[2][8];
    floatx4 z = {0.f, 0.f, 0.f, 0.f};
#pragma unroll
    for (int s = 0; s < 2; s++)
#pragma unroll
        for (int j = 0; j < 8; j++) o[s][j] = z;
    float lsum[2][4] = {{0.f, 0.f, 0.f, 0.f}, {0.f, 0.f, 0.f, 0.f}};

    const float scale_l2e = 0.08838834764831845f * 1.4426950408889634f;  // D^-0.5 * log2(e)
    const float BOUND = 24.0f;

    __syncthreads();  // drain K(0)

    for (int kb = 0; kb <= kbmax; kb++) {
        bool act0 = (kb <= 2 * qt);  // strip0 fully masked on the final iteration

        // issue V(kb) loads (drained at mid-barrier; covered by QK compute)
#pragma unroll
        for (int i = 0; i < 4; i++) {
            gld_lds16(vsrc[i], &Vt[(i * 256 + tid) * 8]);
            vsrc[i] += 64;
        }

        // S = Q K^T for both strips; swizzled K frag reads shared across strips
        floatx4 sc[2][4];
#pragma unroll
        for (int s = 0; s < 2; s++)
#pragma unroll
            for (int jt = 0; jt < 4; jt++) sc[s][jt] = z;
#pragma unroll
        for (int ks = 0; ks < 4; ks++) {
#pragma unroll
            for (int jt = 0; jt < 4; jt++) {
                short8 kf = ld8(&Ks[(jt * 16 + l15) * 128 + (((ks * 4 + quad) ^ l15) * 8)]);
                if (act0)
                    sc[0][jt] = __builtin_amdgcn_mfma_f32_16x16x32_bf16(qf[0][ks], kf, sc[0][jt], 0, 0, 0);
                sc[1][jt] = __builtin_amdgcn_mfma_f32_16x16x32_bf16(qf[1][ks], kf, sc[1][jt], 0, 0, 0);
            }
        }

        // fixed-bound softmax; Ps rows are wave-private (lgkmcnt handles RAW)
#pragma unroll
        for (int s = 0; s < 2; s++) {
            if (s == 0 && !act0) continue;
            bool diag = (kb == 2 * qt + s);
#pragma unroll
            for (int r = 0; r < 4; r++) {
                int rloc = w * 16 + quad * 4 + r;  // row within strip
#pragma unroll
                for (int jt = 0; jt < 4; jt++) {
                    float v = fmaf(sc[s][jt][r], scale_l2e, -BOUND);
                    if (diag && (jt * 16 + l15 > rloc)) v = -1e30f;
                    float p = exp2f(v);
                    lsum[s][r] += p;
                    Ps[(s * 64 + rloc) * PS_STRIDE + jt * 16 + l15] = f2bf(p);
                }
            }
        }

        __syncthreads();  // drain V(kb); all waves' Ks reads complete

        // issue K(kb+1) loads (drained at end-barrier; covered by PV compute)
        if (kb < kbmax) {
#pragma unroll
            for (int i = 0; i < 4; i++) {
                gld_lds16(ksrc[i], &Ks[(i * 256 + tid) * 8]);
                ksrc[i] += (size_t)64 * QKV_N;
            }
        }

        // O += P V ; swizzled V frag reads shared across strips
#pragma unroll
        for (int ks2 = 0; ks2 < 2; ks2++) {
            short8 pf0 = ld8(&Ps[(w * 16 + l15) * PS_STRIDE + ks2 * 32 + quad * 8]);
            short8 pf1 = ld8(&Ps[(64 + w * 16 + l15) * PS_STRIDE + ks2 * 32 + quad * 8]);
#pragma unroll
            for (int jt = 0; jt < 8; jt++) {
                short8 vf = ld8(&Vt[(jt * 16 + l15) * 64 + (((ks2 * 4 + quad) ^ (l15 & 7)) * 8)]);
                if (act0)
                    o[0][jt] = __builtin_amdgcn_mfma_f32_16x16x32_bf16(pf0, vf, o[0][jt], 0, 0, 0);
                o[1][jt] = __builtin_amdgcn_mfma_f32_16x16x32_bf16(pf1, vf, o[1][jt], 0, 0, 0);
            }
        }

        __syncthreads();  // drain K(kb+1); all waves' Vt/Ps reads complete
    }

    // epilogue: one shuffle reduction per row, normalize, store bf16
#pragma unroll
    for (int s = 0; s < 2; s++) {
#pragma unroll
        for (int r = 0; r < 4; r++) {
            float l = lsum[s][r];
#pragma unroll
            for (int mk = 1; mk <= 8; mk <<= 1) l += __shfl_xor(l, mk);
            float inv = 1.f / l;
            int trow = q0 + s * 64 + w * 16 + quad * 4 + r;
            ushort* orow = attn + (size_t)trow * (HQ * D_HEAD) + h * D_HEAD;
#pragma unroll
            for (int jt = 0; jt < 8; jt++)
                orow[jt * 16 + l15] = f2bf(o[s][jt][r] * inv);
        }
    }
}

// ---------------- launch ----------------
extern "C" void kernel_launch(void* const* d_in, const int* in_sizes, int n_in,
                              void* d_out, int out_size, void* d_ws, size_t ws_size,
                              hipStream_t stream) {
    const float* hidden = (const float*)d_in[0];
    const float* cosb = (const float*)d_in[2];
    const float* sinb = (const float*)d_in[3];
    const float* Wq = (const float*)d_in[4];
    const float* Wk = (const float*)d_in[5];
    const float* Wv = (const float*)d_in[6];
    const float* Wo = (const float*)d_in[7];
    float* out = (float*)d_out;

    char* ws = (char*)d_ws;
    ushort* hiddenB = (ushort*)(ws);                          // 16 MB: T x HID bf16
    ushort* WqkvT   = (ushort*)(ws + (size_t)(16u << 20));    // 48 MB: [6144][4096] bf16
    ushort* WoT     = (ushort*)(ws + (size_t)(64u << 20));    // 32 MB: [4096][4096] bf16
    ushort* qkv     = (ushort*)(ws + (size_t)(96u << 20));    // 24 MB: T x 6144 bf16
    ushort* attnO   = (ushort*)(ws + (size_t)(120u << 20));   // 16 MB: T x 4096 bf16
    ushort* VtG     = (ushort*)(ws + (size_t)(136u << 20));   // 4 MB: [HKV][128][2048] bf16
    // total 140 MB

    cast_f32_bf16<<<8192, 256, 0, stream>>>(hidden, hiddenB, T_DIM * HID);
    transpose_cast<<<dim3(64, 64), 256, 0, stream>>>(Wq, WqkvT, HID, 4096);
    transpose_cast<<<dim3(16, 64), 256, 0, stream>>>(Wk, WqkvT + (size_t)4096 * HID, HID, 1024);
    transpose_cast<<<dim3(16, 64), 256, 0, stream>>>(Wv, WqkvT + (size_t)5120 * HID, HID, 1024);
    transpose_cast<<<dim3(64, 64), 256, 0, stream>>>(Wo, WoT, HID, 4096);

    // qkv = hidden @ [Wq|Wk|Wv]   (M=2048, N=6144, K=4096), bf16 out
    gemm256<ushort><<<dim3(8, 24), 512, 0, stream>>>(hiddenB, WqkvT, qkv,
                                                     HID, HID, HID, QKV_N);
    rope_kernel<<<T_DIM, 256, 0, stream>>>(qkv, cosb, sinb);
    transpose_v<<<dim3(64, 4, 8), 256, 0, stream>>>(qkv, VtG);
    attn_kernel<<<dim3(T_DIM / 128, HQ), 256, 0, stream>>>(qkv, VtG, attnO);
    // out = attnO @ Wo  (M=2048, N=4096, K=4096), fp32 out
    gemm_bt<float><<<dim3(16, 32), 256, 0, stream>>>(attnO, WoT, out,
                                                     HID, HID, HID, HID);
}

// Round 3
// 542.122 us; speedup vs baseline: 1.0963x; 1.0510x over previous
//
#include <hip/hip_runtime.h>
#include <hip/hip_bf16.h>
#include <cstdint>
#include <cstddef>

// Problem constants
#define T_DIM   2048
#define HID     4096
#define HQ      32
#define HKV     8
#define D_HEAD  128
#define QKV_N   6144   // 4096 Q + 1024 K + 1024 V
#define KOFF    4096
#define VOFF    5120

typedef __attribute__((ext_vector_type(8))) short short8;   // 8 bf16 (4 VGPRs)
typedef __attribute__((ext_vector_type(4))) float floatx4;  // MFMA C/D frag

__device__ __forceinline__ ushort f2bf(float f) {
    union { float f; uint u; } v; v.f = f;
    uint r = v.u + 0x7fffu + ((v.u >> 16) & 1u);  // RNE
    return (ushort)(r >> 16);
}
__device__ __forceinline__ float bf2f(ushort h) {
    union { uint u; float f; } v; v.u = ((uint)h) << 16; return v.f;
}
// 8 bf16 from 8B-aligned LDS
__device__ __forceinline__ short8 ld8(const ushort* p) {
    uint2 a = *(const uint2*)p, b = *(const uint2*)(p + 4);
    union { uint u[4]; short8 s; } x;
    x.u[0] = a.x; x.u[1] = a.y; x.u[2] = b.x; x.u[3] = b.y;
    return x.s;
}
// async global->LDS, 16B per lane. LDS dest must be wave-uniform base + lane*16.
__device__ __forceinline__ void gld_lds16(const ushort* g, ushort* l) {
    __builtin_amdgcn_global_load_lds(
        (__attribute__((address_space(1))) void*)(g),
        (__attribute__((address_space(3))) void*)(l), 16, 0, 0);
}

// ---------------- elementwise cast fp32 -> bf16 ----------------
__global__ void cast_f32_bf16(const float* __restrict__ in, ushort* __restrict__ out, int n) {
    int i = (blockIdx.x * blockDim.x + threadIdx.x) * 4;
    if (i < n) {
        float4 v = *(const float4*)(in + i);
        ushort4 o;
        o.x = f2bf(v.x); o.y = f2bf(v.y); o.z = f2bf(v.z); o.w = f2bf(v.w);
        *(ushort4*)(out + i) = o;
    }
}

// ---------------- transpose + cast: W[K][N] fp32 -> Wt[N][K] bf16 ----------------
// v2: output phase stores 16 B/lane (short8) -> each 64-lane wave writes 8 rows
// x 128 B fully coalesced (was 8 B/lane). LDS pad 72 keeps rows 16B-aligned for
// ds_read_b128 (row stride 144 B); read-phase conflicts ~2-way (free). Write-phase
// scalar stores are ~8-way conflicted but only 16 stores/thread of 2-clock base —
// negligible vs global BW.
__global__ __launch_bounds__(256) void transpose_cast(const float* __restrict__ W,
                                                      ushort* __restrict__ Wt, int K, int N) {
    __shared__ ushort tile[64][72];
    int n0 = blockIdx.x * 64, k0 = blockIdx.y * 64;
    int tx = threadIdx.x & 15, ty = threadIdx.x >> 4;  // 16 x 16
#pragma unroll
    for (int i = 0; i < 4; i++) {
        int r = ty + i * 16;  // k-row
        float4 v = *(const float4*)&W[(size_t)(k0 + r) * N + n0 + tx * 4];
        tile[tx * 4 + 0][r] = f2bf(v.x);
        tile[tx * 4 + 1][r] = f2bf(v.y);
        tile[tx * 4 + 2][r] = f2bf(v.z);
        tile[tx * 4 + 3][r] = f2bf(v.w);
    }
    __syncthreads();
    // 512 chunk-tasks: out-row nr, 16B chunk c; 8 lanes cover one 128B row segment
#pragma unroll
    for (int i = 0; i < 2; i++) {
        int task = i * 256 + threadIdx.x;
        int nr = task >> 3, c = task & 7;
        short8 o = *(const short8*)&tile[nr][c * 8];
        *(short8*)&Wt[(size_t)(n0 + nr) * K + k0 + c * 8] = o;
    }
}

// ---------------- transpose V slice of qkv -> VtG[kvh][d][t] (t contiguous) ----------------
__global__ void transpose_v(const ushort* __restrict__ qkv, ushort* __restrict__ VtG) {
    __shared__ ushort tile[32][33];
    int t0 = blockIdx.x * 32, d0 = blockIdx.y * 32, kvh = blockIdx.z;
    int tx = threadIdx.x & 31, ty = threadIdx.x >> 5;  // 32 x 8
#pragma unroll
    for (int i = 0; i < 4; i++) {
        int t = t0 + ty + i * 8;
        tile[ty + i * 8][tx] = qkv[(size_t)t * QKV_N + VOFF + kvh * D_HEAD + d0 + tx];
    }
    __syncthreads();
#pragma unroll
    for (int i = 0; i < 4; i++) {
        int d = d0 + ty + i * 8;
        VtG[((size_t)kvh * D_HEAD + d) * T_DIM + t0 + tx] = tile[tx][ty + i * 8];
    }
}

// ---------------- bf16 MFMA GEMM: C[M][N] = A[M][K] * Bt[N][K]^T ----------------
// 128x128 tile, 4 waves (2x2 of 64x64), 16x16x32 MFMA, BK=32, double-buffered.
// 32 KiB LDS + 68 VGPR -> ~2.5-3 blocks/CU: inter-block overlap hides the
// barrier vmcnt drain (m114) — measured faster than 1-block/CU 256^2 pipelines
// on this problem's 192-block geometry (R1/R2 post-mortems).
template <typename OutT>
__global__ __launch_bounds__(256) void gemm_bt(const ushort* __restrict__ A,
                                               const ushort* __restrict__ Bt,
                                               OutT* __restrict__ C,
                                               int K, int lda, int ldb, int ldc) {
    __shared__ ushort As[2][128 * 32];
    __shared__ ushort Bs[2][128 * 32];
    int tid = threadIdx.x;
    int w = tid >> 6, lane = tid & 63, quad = lane >> 4, l15 = lane & 15;
    int wr = (w >> 1) * 64, wc = (w & 1) * 64;
    int m0 = blockIdx.x * 128, n0 = blockIdx.y * 128;

    floatx4 acc[4][4];
    floatx4 z = {0.f, 0.f, 0.f, 0.f};
#pragma unroll
    for (int i = 0; i < 4; i++)
#pragma unroll
        for (int j = 0; j < 4; j++) acc[i][j] = z;

    int arow = tid >> 2, ac = (tid & 3) * 8;
    const ushort* gA0 = A + (size_t)(m0 + arow) * lda + ac;
    const ushort* gA1 = A + (size_t)(m0 + arow + 64) * lda + ac;
    const ushort* gB0 = Bt + (size_t)(n0 + arow) * ldb + ac;
    const ushort* gB1 = Bt + (size_t)(n0 + arow + 64) * ldb + ac;

    gld_lds16(gA0, &As[0][tid * 8]);
    gld_lds16(gA1, &As[0][64 * 32 + tid * 8]);
    gld_lds16(gB0, &Bs[0][tid * 8]);
    gld_lds16(gB1, &Bs[0][64 * 32 + tid * 8]);
    gA0 += 32; gA1 += 32; gB0 += 32; gB1 += 32;

    int cur = 0;
    for (int k0 = 0; k0 < K; k0 += 32, cur ^= 1) {
        __syncthreads();
        if (k0 + 32 < K) {
            gld_lds16(gA0, &As[cur ^ 1][tid * 8]);
            gld_lds16(gA1, &As[cur ^ 1][64 * 32 + tid * 8]);
            gld_lds16(gB0, &Bs[cur ^ 1][tid * 8]);
            gld_lds16(gB1, &Bs[cur ^ 1][64 * 32 + tid * 8]);
            gA0 += 32; gA1 += 32; gB0 += 32; gB1 += 32;
        }

        short8 af[4];
#pragma unroll
        for (int i = 0; i < 4; i++)
            af[i] = *(const short8*)&As[cur][(wr + i * 16 + l15) * 32 + quad * 8];
#pragma unroll
        for (int j = 0; j < 4; j++) {
            short8 bf = *(const short8*)&Bs[cur][(wc + j * 16 + l15) * 32 + quad * 8];
#pragma unroll
            for (int i = 0; i < 4; i++)
                acc[i][j] = __builtin_amdgcn_mfma_f32_16x16x32_bf16(af[i], bf, acc[i][j], 0, 0, 0);
        }
    }

#pragma unroll
    for (int i = 0; i < 4; i++) {
        int row0 = m0 + wr + i * 16 + quad * 4;
#pragma unroll
        for (int j = 0; j < 4; j++) {
            int col = n0 + wc + j * 16 + l15;
#pragma unroll
            for (int r = 0; r < 4; r++) {
                float v = acc[i][j][r];
                if constexpr (sizeof(OutT) == 2)
                    C[(size_t)(row0 + r) * ldc + col] = (OutT)f2bf(v);
                else
                    C[(size_t)(row0 + r) * ldc + col] = v;
            }
        }
    }
}

// ---------------- RoPE in-place on Q and K slices of qkv ----------------
// v2: short8 / float4 vectorized (G13); 320-thread blocks, one 8-wide task per
// thread (40 slices x 8 chunks). cos/sin halves are identical (emb=concat(ang,ang)).
__global__ __launch_bounds__(320) void rope_kernel(ushort* __restrict__ qkv,
                                                   const float* __restrict__ cosb,
                                                   const float* __restrict__ sinb) {
    int t = blockIdx.x;
    ushort* row = qkv + (size_t)t * QKV_N;
    const float* cr = cosb + (size_t)t * D_HEAD;
    const float* sr = sinb + (size_t)t * D_HEAD;
    int task = threadIdx.x;            // 0..319
    int slice = task >> 3, d8 = (task & 7) * 8;
    int col = slice * 128 + d8;
    short8 a = *(const short8*)&row[col];
    short8 b = *(const short8*)&row[col + 64];
    float4 c0 = *(const float4*)&cr[d8], c1 = *(const float4*)&cr[d8 + 4];
    float4 s0 = *(const float4*)&sr[d8], s1 = *(const float4*)&sr[d8 + 4];
    short8 oa, ob;
#pragma unroll
    for (int j = 0; j < 8; j++) {
        float cs = (j < 4) ? ((j == 0) ? c0.x : (j == 1) ? c0.y : (j == 2) ? c0.z : c0.w)
                           : ((j == 4) ? c1.x : (j == 5) ? c1.y : (j == 6) ? c1.z : c1.w);
        float sn = (j < 4) ? ((j == 0) ? s0.x : (j == 1) ? s0.y : (j == 2) ? s0.z : s0.w)
                           : ((j == 4) ? s1.x : (j == 5) ? s1.y : (j == 6) ? s1.z : s1.w);
        float x0 = bf2f((ushort)a[j]), x1 = bf2f((ushort)b[j]);
        oa[j] = (short)f2bf(x0 * cs - x1 * sn);
        ob[j] = (short)f2bf(x1 * cs + x0 * sn);
    }
    *(short8*)&row[col] = oa;
    *(short8*)&row[col + 64] = ob;
}

// ---------------- flash-style causal GQA attention ----------------
#define PS_STRIDE 68

__global__ __launch_bounds__(256, 2) void attn_kernel(const ushort* __restrict__ qkv,
                                                      const ushort* __restrict__ VtG,
                                                      ushort* __restrict__ attn) {
    __shared__ ushort Ks[64 * 128];         // 16384 B, swizzled
    __shared__ ushort Vt[128 * 64];         // 16384 B, swizzled
    __shared__ ushort Ps[128 * PS_STRIDE];  // 17408 B  (total 50176 B -> 3 blocks/CU)

    int qt = (gridDim.x - 1) - blockIdx.x;  // heavy tiles dispatch first
    int h = blockIdx.y;
    int q0 = qt * 128;
    int kbmax = 2 * qt + 1;
    int tid = threadIdx.x, w = tid >> 6, lane = tid & 63, quad = lane >> 4, l15 = lane & 15;
    int kvh = h >> 2;                       // GQA group of 4

    const ushort* kbase = qkv + (size_t)KOFF + (size_t)kvh * D_HEAD;
    const ushort* vbase = VtG + (size_t)kvh * D_HEAD * T_DIM;

    const ushort* ksrc[4];
    const ushort* vsrc[4];
#pragma unroll
    for (int i = 0; i < 4; i++) {
        int cid = i * 256 + tid;
        int kr = cid >> 4, kp = cid & 15, kc = kp ^ (kr & 15);
        ksrc[i] = kbase + (size_t)kr * QKV_N + kc * 8;
        int vr = cid >> 3, vp = cid & 7, vc = vp ^ (vr & 7);
        vsrc[i] = vbase + (size_t)vr * T_DIM + vc * 8;
    }

    // prologue: issue K(0) loads (latency covered by the Q-frag loads below)
#pragma unroll
    for (int i = 0; i < 4; i++) {
        gld_lds16(ksrc[i], &Ks[(i * 256 + tid) * 8]);
        ksrc[i] += (size_t)64 * QKV_N;
    }

    // Q A-frags for both strips, direct from global (one-time scattered read)
    short8 qf[2][4];
#pragma unroll
    for (int s = 0; s < 2; s++) {
        const ushort* qrow = qkv + (size_t)(q0 + s * 64 + w * 16 + l15) * QKV_N + h * D_HEAD + quad * 8;
#pragma unroll
        for (int ks = 0; ks < 4; ks++)
            qf[s][ks] = *(const short8*)(qrow + ks * 32);
    }

    floatx4 o[2][8];
    floatx4 z = {0.f, 0.f, 0.f, 0.f};
#pragma unroll
    for (int s = 0; s < 2; s++)
#pragma unroll
        for (int j = 0; j < 8; j++) o[s][j] = z;
    float lsum[2][4] = {{0.f, 0.f, 0.f, 0.f}, {0.f, 0.f, 0.f, 0.f}};

    const float scale_l2e = 0.08838834764831845f * 1.4426950408889634f;  // D^-0.5 * log2(e)
    const float BOUND = 24.0f;

    __syncthreads();  // drain K(0)

    for (int kb = 0; kb <= kbmax; kb++) {
        bool act0 = (kb <= 2 * qt);  // strip0 fully masked on the final iteration

        // issue V(kb) loads (drained at mid-barrier; covered by QK compute)
#pragma unroll
        for (int i = 0; i < 4; i++) {
            gld_lds16(vsrc[i], &Vt[(i * 256 + tid) * 8]);
            vsrc[i] += 64;
        }

        // S = Q K^T for both strips; swizzled K frag reads shared across strips
        floatx4 sc[2][4];
#pragma unroll
        for (int s = 0; s < 2; s++)
#pragma unroll
            for (int jt = 0; jt < 4; jt++) sc[s][jt] = z;
#pragma unroll
        for (int ks = 0; ks < 4; ks++) {
#pragma unroll
            for (int jt = 0; jt < 4; jt++) {
                short8 kf = ld8(&Ks[(jt * 16 + l15) * 128 + (((ks * 4 + quad) ^ l15) * 8)]);
                if (act0)
                    sc[0][jt] = __builtin_amdgcn_mfma_f32_16x16x32_bf16(qf[0][ks], kf, sc[0][jt], 0, 0, 0);
                sc[1][jt] = __builtin_amdgcn_mfma_f32_16x16x32_bf16(qf[1][ks], kf, sc[1][jt], 0, 0, 0);
            }
        }

        // fixed-bound softmax; Ps rows are wave-private (lgkmcnt handles RAW)
#pragma unroll
        for (int s = 0; s < 2; s++) {
            if (s == 0 && !act0) continue;
            bool diag = (kb == 2 * qt + s);
#pragma unroll
            for (int r = 0; r < 4; r++) {
                int rloc = w * 16 + quad * 4 + r;  // row within strip
#pragma unroll
                for (int jt = 0; jt < 4; jt++) {
                    float v = fmaf(sc[s][jt][r], scale_l2e, -BOUND);
                    if (diag && (jt * 16 + l15 > rloc)) v = -1e30f;
                    float p = exp2f(v);
                    lsum[s][r] += p;
                    Ps[(s * 64 + rloc) * PS_STRIDE + jt * 16 + l15] = f2bf(p);
                }
            }
        }

        __syncthreads();  // drain V(kb); all waves' Ks reads complete

        // issue K(kb+1) loads (drained at end-barrier; covered by PV compute)
        if (kb < kbmax) {
#pragma unroll
            for (int i = 0; i < 4; i++) {
                gld_lds16(ksrc[i], &Ks[(i * 256 + tid) * 8]);
                ksrc[i] += (size_t)64 * QKV_N;
            }
        }

        // O += P V ; swizzled V frag reads shared across strips
#pragma unroll
        for (int ks2 = 0; ks2 < 2; ks2++) {
            short8 pf0 = ld8(&Ps[(w * 16 + l15) * PS_STRIDE + ks2 * 32 + quad * 8]);
            short8 pf1 = ld8(&Ps[(64 + w * 16 + l15) * PS_STRIDE + ks2 * 32 + quad * 8]);
#pragma unroll
            for (int jt = 0; jt < 8; jt++) {
                short8 vf = ld8(&Vt[(jt * 16 + l15) * 64 + (((ks2 * 4 + quad) ^ (l15 & 7)) * 8)]);
                if (act0)
                    o[0][jt] = __builtin_amdgcn_mfma_f32_16x16x32_bf16(pf0, vf, o[0][jt], 0, 0, 0);
                o[1][jt] = __builtin_amdgcn_mfma_f32_16x16x32_bf16(pf1, vf, o[1][jt], 0, 0, 0);
            }
        }

        __syncthreads();  // drain K(kb+1); all waves' Vt/Ps reads complete
    }

    // epilogue: one shuffle reduction per row, normalize, store bf16
#pragma unroll
    for (int s = 0; s < 2; s++) {
#pragma unroll
        for (int r = 0; r < 4; r++) {
            float l = lsum[s][r];
#pragma unroll
            for (int mk = 1; mk <= 8; mk <<= 1) l += __shfl_xor(l, mk);
            float inv = 1.f / l;
            int trow = q0 + s * 64 + w * 16 + quad * 4 + r;
            ushort* orow = attn + (size_t)trow * (HQ * D_HEAD) + h * D_HEAD;
#pragma unroll
            for (int jt = 0; jt < 8; jt++)
                orow[jt * 16 + l15] = f2bf(o[s][jt][r] * inv);
        }
    }
}

// ---------------- launch ----------------
extern "C" void kernel_launch(void* const* d_in, const int* in_sizes, int n_in,
                              void* d_out, int out_size, void* d_ws, size_t ws_size,
                              hipStream_t stream) {
    const float* hidden = (const float*)d_in[0];
    const float* cosb = (const float*)d_in[2];
    const float* sinb = (const float*)d_in[3];
    const float* Wq = (const float*)d_in[4];
    const float* Wk = (const float*)d_in[5];
    const float* Wv = (const float*)d_in[6];
    const float* Wo = (const float*)d_in[7];
    float* out = (float*)d_out;

    char* ws = (char*)d_ws;
    ushort* hiddenB = (ushort*)(ws);                          // 16 MB: T x HID bf16
    ushort* WqkvT   = (ushort*)(ws + (size_t)(16u << 20));    // 48 MB: [6144][4096] bf16
    ushort* WoT     = (ushort*)(ws + (size_t)(64u << 20));    // 32 MB: [4096][4096] bf16
    ushort* qkv     = (ushort*)(ws + (size_t)(96u << 20));    // 24 MB: T x 6144 bf16
    ushort* attnO   = (ushort*)(ws + (size_t)(120u << 20));   // 16 MB: T x 4096 bf16
    ushort* VtG     = (ushort*)(ws + (size_t)(136u << 20));   // 4 MB: [HKV][128][2048] bf16
    // total 140 MB

    cast_f32_bf16<<<8192, 256, 0, stream>>>(hidden, hiddenB, T_DIM * HID);
    transpose_cast<<<dim3(64, 64), 256, 0, stream>>>(Wq, WqkvT, HID, 4096);
    transpose_cast<<<dim3(16, 64), 256, 0, stream>>>(Wk, WqkvT + (size_t)4096 * HID, HID, 1024);
    transpose_cast<<<dim3(16, 64), 256, 0, stream>>>(Wv, WqkvT + (size_t)5120 * HID, HID, 1024);
    transpose_cast<<<dim3(64, 64), 256, 0, stream>>>(Wo, WoT, HID, 4096);

    // qkv = hidden @ [Wq|Wk|Wv]   (M=2048, N=6144, K=4096), bf16 out
    gemm_bt<ushort><<<dim3(16, 48), 256, 0, stream>>>(hiddenB, WqkvT, qkv,
                                                      HID, HID, HID, QKV_N);
    rope_kernel<<<T_DIM, 320, 0, stream>>>(qkv, cosb, sinb);
    transpose_v<<<dim3(64, 4, 8), 256, 0, stream>>>(qkv, VtG);
    attn_kernel<<<dim3(T_DIM / 128, HQ), 256, 0, stream>>>(qkv, VtG, attnO);
    // out = attnO @ Wo  (M=2048, N=4096, K=4096), fp32 out
    gemm_bt<float><<<dim3(16, 32), 256, 0, stream>>>(attnO, WoT, out,
                                                     HID, HID, HID, HID);
}